// Round 9
// baseline (119.634 us; speedup 1.0000x reference)
//
#include <hip/hip_runtime.h>

typedef _Float16 f16x8 __attribute__((ext_vector_type(8)));
typedef __fp16 fp16x2 __attribute__((ext_vector_type(2)));
typedef float f32x4 __attribute__((ext_vector_type(4)));

#define NTHR 256
constexpr float EPS = 1e-5f;
constexpr int NBLOCKS = 4096;   // 1048576 / 256 rows per block

// ---- ws byte offsets (written by prep_kernel every call) ----
// Biases are folded into weight column K=36 (fc1/fc2) / K=18 (fc3) via a
// constant-1 feature that self-propagates (identity rows 36/18/9).
#define TAB_B   0       // f16 [29][8]  embedding-MLP table (464 B used)
#define W1_B    1024    // f16 [48][64]  fc1 (bn1+cbn folded, bias at k=36)
#define W2_B    7168    // f16 [32][64]  fc2 (bn2 folded, bias at k=36)
#define W3_B    11264   // f16 [16][32]  fc3 (bn3 folded, bias at k=18)
#define W4_B    12736   // f32 [16]  fc4 delta row (w at 0..8, bias at 9)

__device__ __forceinline__ ushort f16bits(float x) {
    union { _Float16 h; ushort u; } c; c.h = (_Float16)x; return c.u;
}
__device__ __forceinline__ uint pk2(float a, float b) {
    union { fp16x2 h; uint u; } c; c.h = __builtin_amdgcn_cvt_pkrtz(a, b); return c.u;
}
__device__ __forceinline__ uint pkrelu(float a, float b) {
    return pk2(fmaxf(a, 0.f), fmaxf(b, 0.f));
}
__device__ __forceinline__ f16x8 mk8(uint a, uint b, uint c, uint d) {
    union { uint u[4]; f16x8 v; } f;
    f.u[0] = a; f.u[1] = b; f.u[2] = c; f.u[3] = d;
    return f.v;
}

// Weight A-fragment from global [n][stride] f16: lane m=l&15, k = kb+4g.., kb+16+4g..
__device__ __forceinline__ f16x8 ldw_frag(const ushort* wp, int m, int stride, int kb, int g) {
    const ushort* p = wp + m * stride + kb + 4 * g;
    uint2 lo = *(const uint2*)p;
    uint2 hi = *(const uint2*)(p + 16);
    return mk8(lo.x, lo.y, hi.x, hi.y);
}

__global__ __launch_bounds__(NTHR) void prep_kernel(
    const float* __restrict__ embt, const float* __restrict__ w1,
    const float* __restrict__ b1,   const float* __restrict__ w2,
    const float* __restrict__ b2,
    const float* __restrict__ cbn_g, const float* __restrict__ cbn_b,
    const float* __restrict__ cbn_m, const float* __restrict__ cbn_v,
    const float* __restrict__ f1w, const float* __restrict__ f1b,
    const float* __restrict__ f2w, const float* __restrict__ f2b,
    const float* __restrict__ f3w, const float* __restrict__ f3b,
    const float* __restrict__ f4w, const float* __restrict__ f4b,
    const float* __restrict__ bn1g, const float* __restrict__ bn1b,
    const float* __restrict__ bn1m, const float* __restrict__ bn1v,
    const float* __restrict__ bn2g, const float* __restrict__ bn2b,
    const float* __restrict__ bn2m, const float* __restrict__ bn2v,
    const float* __restrict__ bn3g, const float* __restrict__ bn3b,
    const float* __restrict__ bn3m, const float* __restrict__ bn3v,
    char* __restrict__ ws)
{
    const int t = threadIdx.x;
    ushort* tab = (ushort*)(ws + TAB_B);
    ushort* w1o = (ushort*)(ws + W1_B);
    ushort* w2o = (ushort*)(ws + W2_B);
    ushort* w3o = (ushort*)(ws + W3_B);
    float* w4o = (float*)(ws + W4_B);

    // embedding-MLP lookup table [29][8] f16 (cols 5-7 zero)
    for (int i = t; i < 232; i += NTHR) {
        int j = i / 8, c = i % 8;
        float xe = 0.f;
        if (c < 5) {
            xe = b2[j];
            for (int e = 0; e < 6; e++) {
                float a = b1[j * 6 + e];
                for (int d = 0; d < 6; d++)
                    a += embt[(j * 5 + c) * 6 + d] * w1[j * 36 + d * 6 + e];
                xe += fmaxf(a, 0.f) * w2[j * 6 + e];
            }
        }
        tab[i] = f16bits(xe);
    }
    // fc1 [48][64]: rows<36 = bn1-scaled weights (cbn on cols<7), bias at k=36;
    // row 36 = identity for the constant-1 feature.
    for (int i = t; i < 3072; i += NTHR) {
        int n = i / 64, k = i % 64;
        float v = 0.f;
        if (n < 36) {
            float s1 = bn1g[n] * rsqrtf(bn1v[n] + EPS);
            if (k < 36) {
                v = f1w[n * 36 + k] * s1;
                if (k < 7) v *= cbn_g[k] * rsqrtf(cbn_v[k] + EPS);
            } else if (k == 36) {
                v = f1b[n] * s1 + bn1b[n] - bn1m[n] * s1;
                for (int kk = 0; kk < 7; kk++) {
                    float cs = cbn_g[kk] * rsqrtf(cbn_v[kk] + EPS);
                    float ct = cbn_b[kk] - cbn_m[kk] * cs;
                    v += f1w[n * 36 + kk] * s1 * ct;
                }
            }
        } else if (n == 36 && k == 36) {
            v = 1.f;
        }
        w1o[i] = f16bits(v);
    }
    // fc2 [32][64]: rows<18 weights + bias at k=36; row 18 identity.
    for (int i = t; i < 2048; i += NTHR) {
        int n = i / 64, k = i % 64;
        float v = 0.f;
        if (n < 18) {
            float s = bn2g[n] * rsqrtf(bn2v[n] + EPS);
            if (k < 36) v = f2w[n * 36 + k] * s;
            else if (k == 36) v = f2b[n] * s + bn2b[n] - bn2m[n] * s;
        } else if (n == 18 && k == 36) {
            v = 1.f;
        }
        w2o[i] = f16bits(v);
    }
    // fc3 [16][32]: rows<9 weights + bias at k=18; row 9 identity.
    for (int i = t; i < 512; i += NTHR) {
        int n = i / 32, k = i % 32;
        float v = 0.f;
        if (n < 9) {
            float s = bn3g[n] * rsqrtf(bn3v[n] + EPS);
            if (k < 18) v = f3w[n * 18 + k] * s;
            else if (k == 18) v = f3b[n] * s + bn3b[n] - bn3m[n] * s;
        } else if (n == 9 && k == 18) {
            v = 1.f;
        }
        w3o[i] = f16bits(v);
    }
    // fc4 delta row: w at 0..8, bias at 9
    if (t < 16) w4o[t] = (t < 9) ? (f4w[9 + t] - f4w[t]) : (t == 9 ? (f4b[1] - f4b[0]) : 0.f);
}

// X^T LDS layout: [256 rows][36 f16], 72 B row stride (b64-aligned)
#define XSTRIDE 72

__global__ __launch_bounds__(NTHR, 8) void recovery_net_kernel(
    const float* __restrict__ xcon, const int* __restrict__ xcat,
    const char* __restrict__ ws, float2* __restrict__ out)
{
    __shared__ __align__(16) char s_x[256 * XSTRIDE];   // 18432 B

    const int t = threadIdx.x;
    const int lane = t & 63, w = t >> 6;
    const int l15 = lane & 15, g = lane >> 4;
    const int rb = w * 64;  // this wave's row strip
    const ushort* tabh = (const ushort*)(ws + TAB_B);

    // ---- per-wave staging: wave w fills ONLY rows rb..rb+63; no __syncthreads ----
    {
        const float4* src = (const float4*)(xcon + (size_t)blockIdx.x * 1792 + w * 448);
        for (int idx = lane; idx < 112; idx += 64) {
            float4 v = src[idx];
            int i0 = idx * 4;
#pragma unroll
            for (int e = 0; e < 4; e++) {
                int i = i0 + e;
                unsigned r = (unsigned)i / 7u;
                unsigned k = (unsigned)i - r * 7u;
                float f = (e == 0) ? v.x : (e == 1) ? v.y : (e == 2) ? v.z : v.w;
                *(ushort*)(s_x + (rb + r) * XSTRIDE + 2 * k) = f16bits(f);
            }
        }
        const int4* src2 = (const int4*)(xcat + (size_t)blockIdx.x * 7424 + w * 1856);
        for (int idx = lane; idx < 464; idx += 64) {
            int4 v = src2[idx];
            int i0 = idx * 4;
#pragma unroll
            for (int e = 0; e < 4; e++) {
                int i = i0 + e;
                unsigned r = (unsigned)i / 29u;
                unsigned j = (unsigned)i - r * 29u;
                int c = (e == 0) ? v.x : (e == 1) ? v.y : (e == 2) ? v.z : v.w;
                ushort h = tabh[j * 8 + c];
                *(ushort*)(s_x + (rb + r) * XSTRIDE + 14 + 2 * j) = h;
            }
        }
    }
    asm volatile("s_waitcnt lgkmcnt(0)" ::: "memory");
    __builtin_amdgcn_wave_barrier();

    const ushort* w1p = (const ushort*)(ws + W1_B);
    const ushort* w2p = (const ushort*)(ws + W2_B);
    const ushort* w3p = (const ushort*)(ws + W3_B);
    const float* w4p = (const float*)(ws + W4_B);

    // ---- 4 batch tiles of 16 rows; weights streamed from L1 each tile ----
#pragma unroll 1
    for (int bt = 0; bt < 4; bt++) {
        const char* xr = s_x + (rb + 16 * bt + l15) * XSTRIDE;
        uint2 q0 = *(const uint2*)(xr + 8 * g);        // features 4g..4g+3
        uint2 q1 = *(const uint2*)(xr + 32 + 8 * g);   // features 16+4g..19+4g
        uint2 q2 = *(const uint2*)(xr + 64);           // features 32..35
        f16x8 xb0 = mk8(q0.x, q0.y, q1.x, q1.y);
        // second K-half: g0 -> features 32..35, g1 -> constant-1 at k=36
        uint cw0 = (g == 0) ? q2.x : (g == 1 ? 0x00003C00u : 0u);
        uint cw1 = (g == 0) ? q2.y : 0u;
        f16x8 xb1 = mk8(cw0, cw1, 0u, 0u);

        // fc1 (zero-init acc; bias comes through k=36)
        f32x4 c10 = {0.f, 0.f, 0.f, 0.f};
        f32x4 c11 = {0.f, 0.f, 0.f, 0.f};
        f32x4 c12 = {0.f, 0.f, 0.f, 0.f};
        {
            f16x8 a0 = ldw_frag(w1p, l15,      64, 0, g);
            f16x8 a1 = ldw_frag(w1p, 16 + l15, 64, 0, g);
            f16x8 a2 = ldw_frag(w1p, 32 + l15, 64, 0, g);
            c10 = __builtin_amdgcn_mfma_f32_16x16x32_f16(a0, xb0, c10, 0, 0, 0);
            c11 = __builtin_amdgcn_mfma_f32_16x16x32_f16(a1, xb0, c11, 0, 0, 0);
            c12 = __builtin_amdgcn_mfma_f32_16x16x32_f16(a2, xb0, c12, 0, 0, 0);
            a0 = ldw_frag(w1p, l15,      64, 32, g);
            a1 = ldw_frag(w1p, 16 + l15, 64, 32, g);
            a2 = ldw_frag(w1p, 32 + l15, 64, 32, g);
            c10 = __builtin_amdgcn_mfma_f32_16x16x32_f16(a0, xb1, c10, 0, 0, 0);
            c11 = __builtin_amdgcn_mfma_f32_16x16x32_f16(a1, xb1, c11, 0, 0, 0);
            c12 = __builtin_amdgcn_mfma_f32_16x16x32_f16(a2, xb1, c12, 0, 0, 0);
        }
        // relu + pack: C1 tiles are exactly fc2's B-fragments (const-1 self-propagates)
        f16x8 h0 = mk8(pkrelu(c10.x, c10.y), pkrelu(c10.z, c10.w),
                       pkrelu(c11.x, c11.y), pkrelu(c11.z, c11.w));
        f16x8 h1 = mk8(pkrelu(c12.x, c12.y), pkrelu(c12.z, c12.w), 0u, 0u);

        // fc2
        f32x4 c20 = {0.f, 0.f, 0.f, 0.f};
        f32x4 c21 = {0.f, 0.f, 0.f, 0.f};
        {
            f16x8 b0 = ldw_frag(w2p, l15,      64, 0, g);
            f16x8 b1 = ldw_frag(w2p, 16 + l15, 64, 0, g);
            c20 = __builtin_amdgcn_mfma_f32_16x16x32_f16(b0, h0, c20, 0, 0, 0);
            c21 = __builtin_amdgcn_mfma_f32_16x16x32_f16(b1, h0, c21, 0, 0, 0);
            b0 = ldw_frag(w2p, l15,      64, 32, g);
            b1 = ldw_frag(w2p, 16 + l15, 64, 32, g);
            c20 = __builtin_amdgcn_mfma_f32_16x16x32_f16(b0, h1, c20, 0, 0, 0);
            c21 = __builtin_amdgcn_mfma_f32_16x16x32_f16(b1, h1, c21, 0, 0, 0);
        }

        // fc3
        f16x8 h2 = mk8(pkrelu(c20.x, c20.y), pkrelu(c20.z, c20.w),
                       pkrelu(c21.x, c21.y), pkrelu(c21.z, c21.w));
        f32x4 c3 = {0.f, 0.f, 0.f, 0.f};
        {
            f16x8 a3 = ldw_frag(w3p, l15, 32, 0, g);
            c3 = __builtin_amdgcn_mfma_f32_16x16x32_f16(a3, h2, c3, 0, 0, 0);
        }

        // fc4 delta (w4[9]=bias hits h3[9]=1) + sigmoid
        float4 w4v = *(const float4*)(w4p + 4 * g);
        float part = fmaxf(c3.x, 0.f) * w4v.x + fmaxf(c3.y, 0.f) * w4v.y +
                     fmaxf(c3.z, 0.f) * w4v.z + fmaxf(c3.w, 0.f) * w4v.w;
        part += __shfl_xor(part, 16);
        part += __shfl_xor(part, 32);
        float p1 = 1.f / (1.f + __expf(-part));
        if (g == 0)
            out[blockIdx.x * 256 + rb + 16 * bt + l15] = make_float2(1.f - p1, p1);
    }
}

extern "C" void kernel_launch(void* const* d_in, const int* in_sizes, int n_in,
                              void* d_out, int out_size, void* d_ws, size_t ws_size,
                              hipStream_t stream) {
    (void)in_sizes; (void)n_in; (void)ws_size; (void)out_size;
    char* ws = (char*)d_ws;
    prep_kernel<<<1, NTHR, 0, stream>>>(
        (const float*)d_in[2],  (const float*)d_in[3],
        (const float*)d_in[4],  (const float*)d_in[5],
        (const float*)d_in[6],
        (const float*)d_in[7],  (const float*)d_in[8],
        (const float*)d_in[9],  (const float*)d_in[10],
        (const float*)d_in[11], (const float*)d_in[12],
        (const float*)d_in[13], (const float*)d_in[14],
        (const float*)d_in[15], (const float*)d_in[16],
        (const float*)d_in[17], (const float*)d_in[18],
        (const float*)d_in[19], (const float*)d_in[20],
        (const float*)d_in[21], (const float*)d_in[22],
        (const float*)d_in[23], (const float*)d_in[24],
        (const float*)d_in[25], (const float*)d_in[26],
        (const float*)d_in[27], (const float*)d_in[28],
        (const float*)d_in[29], (const float*)d_in[30],
        ws);
    recovery_net_kernel<<<NBLOCKS, NTHR, 0, stream>>>(
        (const float*)d_in[0], (const int*)d_in[1], ws, (float2*)d_out);
}